// Round 1
// baseline (222.825 us; speedup 1.0000x reference)
//
#include <hip/hip_runtime.h>

#define BATCH 128
#define NPTS  4096
#define EPT   8                    // cells per thread
#define WREG  (64 * EPT)           // 512-cell compute region per wave
#define HALOC 104                  // halo cells per side (13 threads * 8 >= 99 steps)
#define OWN   (WREG - 2 * HALOC)   // 304 owned cells per interior wave
#define SEGS  14                   // ceil(4096 / 304); last seg owns 144
#define TPB   64                   // one wave per block: 1792 blocks = exactly 7 waves/CU

// Halved-coefficient flux: g(u) = 0.5*f(u), ah(u) = 0.5*|f'(u)|
// f  = 1.5u + 0.75b u^2 + (-0.5-2b) u^3 + 1.5b u^4 - 0.25b u^6,  b = beta/12
// f' = 1.5 + 1.5b u - (1.5+6b) u^2 + 6b u^3 - 1.5b u^5
__device__ __forceinline__ void flux_eval(float u, float& g, float& ah) {
    constexpr float b  = 0.1f / 12.0f;
    constexpr float c6 = 0.5f * (-0.25f * b);
    constexpr float c4 = 0.5f * ( 1.5f  * b);
    constexpr float c3 = 0.5f * (-0.5f - 2.0f * b);
    constexpr float c2 = 0.5f * ( 0.75f * b);
    constexpr float c1 = 0.5f * ( 1.5f);
    constexpr float d5 = 0.5f * (-1.5f * b);
    constexpr float d3 = 0.5f * ( 6.0f * b);
    constexpr float d2 = 0.5f * (-(1.5f + 6.0f * b));
    constexpr float d1 = 0.5f * ( 1.5f * b);
    constexpr float d0 = 0.5f * ( 1.5f);

    float t = c6 * u;            // c5 == 0
    t = fmaf(t, u, c4);
    t = fmaf(t, u, c3);
    t = fmaf(t, u, c2);
    t = fmaf(t, u, c1);
    g = u * t;

    float e = d5 * u;            // d4 == 0
    e = fmaf(e, u, d3);
    e = fmaf(e, u, d2);
    e = fmaf(e, u, d1);
    e = fmaf(e, u, d0);
    ah = fabsf(e);
}

// Wave-independent halo decomposition: no LDS, no barriers.
// Each wave evolves a 512-cell region for all 99 steps; contamination from
// the region edges advances 1 cell/step, so the central OWN=304 cells
// (HALOC=104 >= 99 on each side) stay exact through the final step.
// Neighbor cells across thread boundaries travel via intra-wave shuffles.
__global__ __launch_bounds__(TPB) void pde_wave_indep(
        const float* __restrict__ init,
        const int*   __restrict__ stepnum_p,
        float*       __restrict__ out) {
    const int wid  = blockIdx.x;
    const int lane = threadIdx.x;                      // 0..63
    const int row  = wid / SEGS;
    const int seg  = wid - row * SEGS;

    const int ownlo = seg * OWN;                       // 0, 304, ..., 3952
    // Clamp region into the row; edge segments align with the domain edge
    // where the boundary condition (not halo) protects validity.
    const int base  = min(max(ownlo - HALOC, 0), NPTS - WREG);
    const int c0    = base + lane * EPT;               // 32B-aligned (base % 8 == 0)
    const bool ownstore = (c0 >= ownlo) && (c0 < ownlo + OWN) && (c0 < NPTS);
    const bool bcL = (seg == 0) && (lane == 0);        // owns cell 0
    const bool bcR = (seg == SEGS - 1) && (lane == 63);// owns cell N-1
    const int stepnum = *stepnum_p;

    const float* ip = init + (size_t)row * NPTS + c0;
    const float4 A  = *(const float4*)ip;
    const float4 Bv = *(const float4*)(ip + 4);
    float v[EPT] = {A.x, A.y, A.z, A.w, Bv.x, Bv.y, Bv.z, Bv.w};

    float* op = out + (size_t)row * NPTS + c0;
    const size_t zstride = (size_t)BATCH * NPTS;

    if (ownstore) {                                    // out[step=0] = init verbatim
        *(float4*)op       = A;
        *(float4*)(op + 4) = Bv;
    }

    for (int s = 1; s < stepnum; ++s) {
        // Edge exchange: lane l gets lane l-1's last cell and lane l+1's first.
        // At wave edges the shuffle returns the lane's own value — garbage that
        // only ever feeds halo cells (or the BC-overwritten boundary cell).
        const float vl = __shfl_up(v[EPT - 1], 1, 64);
        const float vr = __shfl_down(v[0], 1, 64);

        float vv[EPT + 2];
        vv[0] = vl;
#pragma unroll
        for (int i = 0; i < EPT; ++i) vv[i + 1] = v[i];
        vv[EPT + 1] = vr;

        float g[EPT + 2], a[EPT + 2];
#pragma unroll
        for (int i = 0; i < EPT + 2; ++i) flux_eval(vv[i], g[i], a[i]);

        float fh[EPT + 1];
#pragma unroll
        for (int m = 0; m < EPT + 1; ++m)
            fh[m] = g[m] + g[m + 1] - fmaxf(a[m], a[m + 1]) * (vv[m + 1] - vv[m]);

#pragma unroll
        for (int i = 0; i < EPT; ++i)                  // r = DT/DX = 0.5 exactly
            v[i] = fmaf(-0.5f, fh[i + 1] - fh[i], v[i]);

        if (bcL) v[0] = v[1];                          // u_new[0]   = u_new[1]
        if (bcR) v[EPT - 1] = v[EPT - 2];              // u_new[N-1] = u_new[N-2]

        op += zstride;
        if (ownstore) {
            *(float4*)op       = make_float4(v[0], v[1], v[2], v[3]);
            *(float4*)(op + 4) = make_float4(v[4], v[5], v[6], v[7]);
        }
    }
}

extern "C" void kernel_launch(void* const* d_in, const int* in_sizes, int n_in,
                              void* d_out, int out_size, void* d_ws, size_t ws_size,
                              hipStream_t stream) {
    const float* init  = (const float*)d_in[0];
    const int*   steps = (const int*)d_in[1];
    float*       out   = (float*)d_out;
    pde_wave_indep<<<BATCH * SEGS, TPB, 0, stream>>>(init, steps, out);
}